// Round 9
// baseline (324.116 us; speedup 1.0000x reference)
//
#include <hip/hip_runtime.h>
#include <hip/hip_bf16.h>
#include <math.h>

#define N_NODES 100000
#define N_EDGES 1600000
#define DIM_IN 165
#define DIM_HID 128
#define K_PAD 192                 // 6 chunks of 32
#define NBUCK 391                 // ceil(100000/256) coarse buckets (dst>>8)
#define EPB 16384                 // edges per block in phases A/B
#define NHB 98                    // ceil(N_EDGES/EPB)
#define CAP 6144                  // per-bucket edge capacity (mean 4092, sigma~64)

typedef __attribute__((ext_vector_type(8))) short short8v;   // 8 bf16 (4 VGPR)
typedef __attribute__((ext_vector_type(4))) float f32x4;     // MFMA acc

// ---------- detect edge dtype (int32 vs int64) + zero bucket counts ----------
__global__ void k_detect(const int* __restrict__ e32, int* __restrict__ flag,
                         int* __restrict__ gcount) {
    int t = threadIdx.x;
    if (t == 0) {
        int z = 0;
        for (int k = 0; k < 16; ++k) z |= e32[2 * k + 1];
        flag[0] = (z == 0) ? 1 : 0;   // 1 => int64 little-endian
    }
    if (t < NBUCK) gcount[t] = 0;
}

// ---------- phase A: per-block bucket histogram + claim global bases ----------
__global__ void k_histB(const int* __restrict__ e32, const int* __restrict__ flag,
                        int* __restrict__ gcount, int* __restrict__ blockBase) {
    __shared__ int lc[NBUCK];
    int t = threadIdx.x;
    for (int i = t; i < NBUCK; i += 256) lc[i] = 0;
    __syncthreads();
    int isI64 = flag[0];
    int base = blockIdx.x * EPB;
    int lim = base + EPB; if (lim > N_EDGES) lim = N_EDGES;
    const long long* e64 = (const long long*)e32;
    for (int i = base + t; i < lim; i += 256) {
        int d = isI64 ? (int)e64[N_EDGES + i] : e32[N_EDGES + i];
        atomicAdd(&lc[d >> 8], 1);
    }
    __syncthreads();
    for (int b = t; b < NBUCK; b += 256)
        blockBase[blockIdx.x * NBUCK + b] = atomicAdd(&gcount[b], lc[b]);
}

// ---------- scan 391 bucket counts -> bucketStart; also row_ptr[N] ----------
__global__ void k_scanb(const int* __restrict__ gcount, int* __restrict__ bucketStart,
                        int* __restrict__ row_ptr) {
    __shared__ int s[512];
    int t = threadIdx.x;
    s[t] = (t < NBUCK) ? gcount[t] : 0;
    __syncthreads();
    for (int o = 1; o < 512; o <<= 1) {
        int v = s[t]; int a = (t >= o) ? s[t - o] : 0;
        __syncthreads(); s[t] = v + a; __syncthreads();
    }
    if (t < NBUCK) bucketStart[t + 1] = s[t];
    if (t == 0) { bucketStart[0] = 0; row_ptr[N_NODES] = N_EDGES; }
}

// ---------- phase B: scatter (src,dst) pairs into bucket-major order ----------
__global__ void k_scatterB(const int* __restrict__ e32, const int* __restrict__ flag,
                           const int* __restrict__ bucketStart, const int* __restrict__ blockBase,
                           int2* __restrict__ pairs) {
    __shared__ int lcur[NBUCK];
    int t = threadIdx.x;
    for (int b = t; b < NBUCK; b += 256)
        lcur[b] = bucketStart[b] + blockBase[blockIdx.x * NBUCK + b];
    __syncthreads();
    int isI64 = flag[0];
    int base = blockIdx.x * EPB;
    int lim = base + EPB; if (lim > N_EDGES) lim = N_EDGES;
    const long long* e64 = (const long long*)e32;
    for (int i = base + t; i < lim; i += 256) {
        int s, d;
        if (isI64) { s = (int)e64[i]; d = (int)e64[N_EDGES + i]; }
        else       { s = e32[i];      d = e32[N_EDGES + i]; }
        int pos = atomicAdd(&lcur[d >> 8], 1);
        pairs[pos] = make_int2(s, d);     // ~42-edge contiguous runs per (block,bucket)
    }
}

// ---------- phase C: per-bucket counting sort in LDS -> esrc + row_ptr ----------
__global__ void k_sortB(const int2* __restrict__ pairs, const int* __restrict__ bucketStart,
                        int* __restrict__ row_ptr, int* __restrict__ esrc) {
    __shared__ int srcb[CAP];       // packed: src | (local_dst<<20)
    __shared__ int cnt[256];
    __shared__ int scn[256];
    int t = threadIdx.x;
    int b = blockIdx.x;
    int s0 = bucketStart[b], s1 = bucketStart[b + 1];
    int n = s1 - s0; if (n > CAP) n = CAP;   // never triggers (32-sigma margin)
    cnt[t] = 0;
    __syncthreads();
    for (int i = t; i < n; i += 256) {
        int2 p = pairs[s0 + i];
        int ld = p.y & 255;
        srcb[i] = p.x | (ld << 20);
        atomicAdd(&cnt[ld], 1);
    }
    __syncthreads();
    // exclusive scan of cnt
    scn[t] = cnt[t];
    __syncthreads();
    for (int o = 1; o < 256; o <<= 1) {
        int v = scn[t]; int a = (t >= o) ? scn[t - o] : 0;
        __syncthreads(); scn[t] = v + a; __syncthreads();
    }
    int excl = scn[t] - cnt[t];
    int node = b * 256 + t;
    if (node < N_NODES) row_ptr[node] = s0 + excl;
    __syncthreads();
    cnt[t] = excl;                  // reuse as cursor
    __syncthreads();
    for (int i = t; i < n; i += 256) {
        int v = srcb[i];
        int ld = v >> 20;
        int r = atomicAdd(&cnt[ld], 1);
        esrc[s0 + r] = v & 0xFFFFF; // 16KB window, single block/XCD -> L2 absorbs
    }
}

// ---------- W prep: pack [Wrel1 ; Wroot1] as bf16 frag-layout Wpk[k>>3][n][k&7] ----------
__global__ void k_prepw(const float* __restrict__ Wrel1, const float* __restrict__ Wroot1,
                        unsigned short* __restrict__ Wpk) {
    int idx = blockIdx.x * 256 + threadIdx.x;
    if (idx < (K_PAD / 8) * 256 * 8) {
        int j = idx & 7;
        int n = (idx >> 3) & 255;
        int p = idx >> 11;
        int k = p * 8 + j;
        float v = 0.f;
        if (k < DIM_IN) v = (n < 128) ? Wrel1[n * DIM_IN + k] : Wroot1[(n - 128) * DIM_IN + k];
        unsigned u = __float_as_uint(v);
        u += 0x7FFFu + ((u >> 16) & 1u);     // RNE to bf16
        Wpk[idx] = (unsigned short)(u >> 16);
    }
}

// ---------- layer-1 via MFMA: [y_rel | y_root] = x @ [Wrel1;Wroot1]^T ----------
// x split hi+lo bf16 (2 MFMA passes, same acc). y_rel bf16, y_root fp32.
__launch_bounds__(256, 4)
__global__ void k_gemm_mfma(const float* __restrict__ x, const unsigned short* __restrict__ Wpk,
                            unsigned short* __restrict__ y_rel, float* __restrict__ y_root) {
    __shared__ unsigned short lh[32][232];
    __shared__ unsigned short ll[32][232];
    int tid = threadIdx.x;
    int base = blockIdx.x * 32;

    const float4* xg = (const float4*)(x + (size_t)base * DIM_IN);
    for (int i = tid; i < 1320; i += 256) {
        float4 v = xg[i];
        int fi = i * 4;
        #pragma unroll
        for (int e = 0; e < 4; ++e) {
            int idx = fi + e;
            int r = idx / DIM_IN;
            int k = idx - r * DIM_IN;
            float f = (e == 0) ? v.x : (e == 1) ? v.y : (e == 2) ? v.z : v.w;
            unsigned u = __float_as_uint(f);
            unsigned short hi = (unsigned short)(u >> 16);
            float fhi = __uint_as_float(u & 0xFFFF0000u);
            float lo = f - fhi;
            unsigned short lob = (unsigned short)(__float_as_uint(lo) >> 16);
            lh[r][k] = hi;
            ll[r][k] = lob;
        }
    }
    for (int i = tid; i < 32 * (K_PAD - DIM_IN); i += 256) {
        int r = i / (K_PAD - DIM_IN);
        int k = DIM_IN + (i - r * (K_PAD - DIM_IN));
        lh[r][k] = 0; ll[r][k] = 0;
    }
    __syncthreads();

    int w = tid >> 6, l = tid & 63;
    int rowg = w & 1;
    int colh = w >> 1;
    int m = l & 15, kg = l >> 4;
    int arow = rowg * 16 + m;

    f32x4 acc[8];
    #pragma unroll
    for (int t = 0; t < 8; ++t) acc[t] = (f32x4){0.f, 0.f, 0.f, 0.f};

    const short8v* ap_h = (const short8v*)(&lh[arow][0]);
    const short8v* ap_l = (const short8v*)(&ll[arow][0]);
    const short8v* bp   = (const short8v*)Wpk;
    int bidx = kg * 256 + colh * 128 + m;

    #pragma unroll
    for (int kc = 0; kc < 6; ++kc) {
        short8v ah = ap_h[kc * 4 + kg];
        short8v al = ap_l[kc * 4 + kg];
        short8v bfrag[8];
        #pragma unroll
        for (int t = 0; t < 8; ++t) bfrag[t] = bp[bidx + kc * 1024 + t * 16];
        #pragma unroll
        for (int t = 0; t < 8; ++t)
            acc[t] = __builtin_amdgcn_mfma_f32_16x16x32_bf16(ah, bfrag[t], acc[t], 0, 0, 0);
        #pragma unroll
        for (int t = 0; t < 8; ++t)
            acc[t] = __builtin_amdgcn_mfma_f32_16x16x32_bf16(al, bfrag[t], acc[t], 0, 0, 0);
    }

    int orow = base + rowg * 16 + kg * 4;
    if (colh == 0) {
        #pragma unroll
        for (int t = 0; t < 8; ++t) {
            #pragma unroll
            for (int q = 0; q < 4; ++q) {
                unsigned u = __float_as_uint(acc[t][q]);
                u += 0x7FFFu + ((u >> 16) & 1u);
                y_rel[(size_t)(orow + q) * 128 + t * 16 + m] = (unsigned short)(u >> 16);
            }
        }
    } else {
        #pragma unroll
        for (int t = 0; t < 8; ++t) {
            #pragma unroll
            for (int q = 0; q < 4; ++q)
                y_root[(size_t)(orow + q) * 128 + t * 16 + m] = acc[t][q];
        }
    }
}

// ---------- fused agg v2: quarter-wave edges. Wave per node; lane quarter q
// handles edge k+q via dwordx4 (16B = 8 cols). esrc preloaded coalesced and
// broadcast via shfl. agg -> h=relu(agg+b+y_root) -> s,r dots. ----------
__launch_bounds__(256, 8)
__global__ void k_agg(const unsigned short* __restrict__ y_rel, const float* __restrict__ y_root,
                      const int* __restrict__ row_ptr, const int* __restrict__ esrc,
                      const float* __restrict__ b_rel1, const float* __restrict__ W_rel2,
                      const float* __restrict__ W_root2,
                      float* __restrict__ s_out, float* __restrict__ r_out) {
    int node = blockIdx.x * 4 + (threadIdx.x >> 6);
    int lane = threadIdx.x & 63;
    int li = lane & 15;            // column group: owns cols 8*li .. 8*li+7
    int qid = lane >> 4;           // quarter 0..3 -> edge k+qid
    const uint4* yr = (const uint4*)y_rel;   // row = 16 uint4 of 16B

    int e0 = row_ptr[node], e1 = row_ptr[node + 1];
    float a0 = 0.f, a1 = 0.f, a2 = 0.f, a3 = 0.f;
    float a4 = 0.f, a5 = 0.f, a6 = 0.f, a7 = 0.f;

    for (int eb = e0; eb < e1; eb += 64) {   // refill window (deg>64 never in practice)
        int cnt = e1 - eb; if (cnt > 64) cnt = 64;
        int ed = (eb + lane < e1) ? esrc[eb + lane] : 0;   // one coalesced load
        int kfull = cnt & ~3;
        for (int k = 0; k < kfull; k += 4) {
            int src = __shfl(ed, k + qid);
            uint4 v = yr[(size_t)src * 16 + li];
            a0 += __uint_as_float(v.x << 16); a1 += __uint_as_float(v.x & 0xFFFF0000u);
            a2 += __uint_as_float(v.y << 16); a3 += __uint_as_float(v.y & 0xFFFF0000u);
            a4 += __uint_as_float(v.z << 16); a5 += __uint_as_float(v.z & 0xFFFF0000u);
            a6 += __uint_as_float(v.w << 16); a7 += __uint_as_float(v.w & 0xFFFF0000u);
        }
        if (kfull < cnt) {                    // tail: quarters beyond cnt masked
            int src = __shfl(ed, (kfull + qid < cnt) ? (kfull + qid) : kfull);
            if (kfull + qid < cnt) {
                uint4 v = yr[(size_t)src * 16 + li];
                a0 += __uint_as_float(v.x << 16); a1 += __uint_as_float(v.x & 0xFFFF0000u);
                a2 += __uint_as_float(v.y << 16); a3 += __uint_as_float(v.y & 0xFFFF0000u);
                a4 += __uint_as_float(v.z << 16); a5 += __uint_as_float(v.z & 0xFFFF0000u);
                a6 += __uint_as_float(v.w << 16); a7 += __uint_as_float(v.w & 0xFFFF0000u);
            }
        }
    }
    // combine quarters (lanes with same li across qid hold partial sums)
    #pragma unroll
    for (int o = 16; o <= 32; o <<= 1) {
        a0 += __shfl_xor(a0, o); a1 += __shfl_xor(a1, o);
        a2 += __shfl_xor(a2, o); a3 += __shfl_xor(a3, o);
        a4 += __shfl_xor(a4, o); a5 += __shfl_xor(a5, o);
        a6 += __shfl_xor(a6, o); a7 += __shfl_xor(a7, o);
    }

    // epilogue: lane owns cols 8li..8li+7 (duplicated across quarters)
    const float4* bb = (const float4*)(b_rel1 + 8 * li);
    const float4* rt = (const float4*)(y_root + (size_t)node * 128 + 8 * li);
    const float4* w2 = (const float4*)(W_rel2 + 8 * li);
    const float4* wo = (const float4*)(W_root2 + 8 * li);
    float4 b0 = bb[0], b1 = bb[1];
    float4 r0 = rt[0], r1 = rt[1];
    float4 p0 = w2[0], p1 = w2[1];
    float4 q0 = wo[0], q1 = wo[1];
    float h0 = fmaxf(a0 + b0.x + r0.x, 0.f), h1 = fmaxf(a1 + b0.y + r0.y, 0.f);
    float h2 = fmaxf(a2 + b0.z + r0.z, 0.f), h3 = fmaxf(a3 + b0.w + r0.w, 0.f);
    float h4 = fmaxf(a4 + b1.x + r1.x, 0.f), h5 = fmaxf(a5 + b1.y + r1.y, 0.f);
    float h6 = fmaxf(a6 + b1.z + r1.z, 0.f), h7 = fmaxf(a7 + b1.w + r1.w, 0.f);
    float sd = h0 * p0.x + h1 * p0.y + h2 * p0.z + h3 * p0.w
             + h4 * p1.x + h5 * p1.y + h6 * p1.z + h7 * p1.w;
    float rd = h0 * q0.x + h1 * q0.y + h2 * q0.z + h3 * q0.w
             + h4 * q1.x + h5 * q1.y + h6 * q1.z + h7 * q1.w;
    #pragma unroll
    for (int o = 1; o <= 8; o <<= 1) {
        sd += __shfl_xor(sd, o);
        rd += __shfl_xor(rd, o);
    }
    if (lane == 0) { s_out[node] = sd; r_out[node] = rd; }
}

// ---------- final v2: wave per node; parallel gather of s[src]; shfl reduce ----------
__launch_bounds__(256, 8)
__global__ void k_final(const float* __restrict__ s_in, const float* __restrict__ r_in,
                        const int* __restrict__ row_ptr, const int* __restrict__ esrc,
                        const float* __restrict__ b_rel2, float* __restrict__ out) {
    int node = blockIdx.x * 4 + (threadIdx.x >> 6);
    int lane = threadIdx.x & 63;
    int e0 = row_ptr[node], e1 = row_ptr[node + 1];
    float sum = 0.f;
    for (int eb = e0; eb < e1; eb += 64) {
        if (eb + lane < e1) sum += s_in[esrc[eb + lane]];   // s_in 400KB, L2-hot
    }
    #pragma unroll
    for (int o = 1; o <= 32; o <<= 1) sum += __shfl_xor(sum, o);
    if (lane == 0) {
        float z = sum + b_rel2[0] + r_in[node];
        out[node] = 1.f / (1.f + expf(-z));
    }
}

extern "C" void kernel_launch(void* const* d_in, const int* in_sizes, int n_in,
                              void* d_out, int out_size, void* d_ws, size_t ws_size,
                              hipStream_t stream) {
    const float* x      = (const float*)d_in[0];
    const int*   eidx   = (const int*)d_in[1];
    const float* Wrel1  = (const float*)d_in[2];
    const float* brel1  = (const float*)d_in[3];
    const float* Wroot1 = (const float*)d_in[4];
    const float* Wrel2  = (const float*)d_in[5];
    const float* brel2  = (const float*)d_in[6];
    const float* Wroot2 = (const float*)d_in[7];
    float* out = (float*)d_out;

    char* basep = (char*)d_ws;
    size_t off = 0;
    auto alloc = [&](size_t bytes) -> void* {
        off = (off + 511) & ~(size_t)511;
        void* r = basep + off;
        off += bytes;
        return r;
    };
    // --- persistent ---
    int*   flag        = (int*)alloc(4);
    unsigned short* Wpk = (unsigned short*)alloc((size_t)(K_PAD / 8) * 256 * 8 * 2);
    int*   row_ptr     = (int*)alloc((size_t)(N_NODES + 1) * 4);
    int*   esrc        = (int*)alloc((size_t)N_EDGES * 4);
    float* s_buf       = (float*)alloc((size_t)N_NODES * 4);
    float* r_buf       = (float*)alloc((size_t)N_NODES * 4);
    int*   bucketStart = (int*)alloc((size_t)(NBUCK + 1) * 4);
    int*   gcount      = (int*)alloc((size_t)NBUCK * 4);
    // --- union region: sort scratch (dead after k_sortB) vs GEMM outputs ---
    size_t union_base = (off + 511) & ~(size_t)511;
    off = union_base;
    int2*  pairs     = (int2*)alloc((size_t)N_EDGES * 8);
    int*   blockBase = (int*)alloc((size_t)NHB * NBUCK * 4);
    off = union_base;
    unsigned short* y_rel  = (unsigned short*)alloc((size_t)N_NODES * DIM_HID * 2);
    float*          y_root = (float*)alloc((size_t)N_NODES * DIM_HID * 4);

    hipLaunchKernelGGL(k_detect,   dim3(1),     dim3(512), 0, stream, eidx, flag, gcount);
    hipLaunchKernelGGL(k_histB,    dim3(NHB),   dim3(256), 0, stream, eidx, flag, gcount, blockBase);
    hipLaunchKernelGGL(k_scanb,    dim3(1),     dim3(512), 0, stream, gcount, bucketStart, row_ptr);
    hipLaunchKernelGGL(k_scatterB, dim3(NHB),   dim3(256), 0, stream, eidx, flag, bucketStart, blockBase, pairs);
    hipLaunchKernelGGL(k_sortB,    dim3(NBUCK), dim3(256), 0, stream, pairs, bucketStart, row_ptr, esrc);
    hipLaunchKernelGGL(k_prepw,    dim3(192),   dim3(256), 0, stream, Wrel1, Wroot1, Wpk);
    hipLaunchKernelGGL(k_gemm_mfma,dim3(3125),  dim3(256), 0, stream, x, Wpk, y_rel, y_root);
    hipLaunchKernelGGL(k_agg,      dim3(25000), dim3(256), 0, stream, y_rel, y_root, row_ptr, esrc,
                       brel1, Wrel2, Wroot2, s_buf, r_buf);
    hipLaunchKernelGGL(k_final,    dim3(25000), dim3(256), 0, stream, s_buf, r_buf, row_ptr, esrc,
                       brel2, out);
}

// Round 10
// 308.965 us; speedup vs baseline: 1.0490x; 1.0490x over previous
//
#include <hip/hip_runtime.h>
#include <hip/hip_bf16.h>
#include <math.h>

#define N_NODES 100000
#define N_EDGES 1600000
#define DIM_IN 165
#define DIM_HID 128
#define K_PAD 192                 // 6 chunks of 32
#define NBUCK 391                 // ceil(100000/256) coarse buckets (dst>>8)
#define EPB 16384                 // edges per block in phases A/B
#define NHB 98                    // ceil(N_EDGES/EPB)
#define CAP 6144                  // per-bucket edge capacity (mean 4092, sigma~64)

typedef __attribute__((ext_vector_type(8))) short short8v;   // 8 bf16 (4 VGPR)
typedef __attribute__((ext_vector_type(4))) float f32x4;     // MFMA acc

// ---------- fused init: block 0 = dtype detect + zero gcount; blocks 1.. = W pack ----------
__global__ void k_init(const int* __restrict__ e32, int* __restrict__ flag,
                       int* __restrict__ gcount,
                       const float* __restrict__ Wrel1, const float* __restrict__ Wroot1,
                       unsigned short* __restrict__ Wpk) {
    int b = blockIdx.x;
    int t = threadIdx.x;
    if (b == 0) {
        if (t == 0) {
            int z = 0;
            for (int k = 0; k < 16; ++k) z |= e32[2 * k + 1];
            flag[0] = (z == 0) ? 1 : 0;   // 1 => int64 little-endian
        }
        for (int i = t; i < NBUCK; i += 256) gcount[i] = 0;
    } else {
        int idx = (b - 1) * 256 + t;      // 192*256 = 49152 = (K_PAD/8)*256*8 exactly
        int j = idx & 7;
        int n = (idx >> 3) & 255;
        int p = idx >> 11;
        int k = p * 8 + j;
        float v = 0.f;
        if (k < DIM_IN) v = (n < 128) ? Wrel1[n * DIM_IN + k] : Wroot1[(n - 128) * DIM_IN + k];
        unsigned u = __float_as_uint(v);
        u += 0x7FFFu + ((u >> 16) & 1u);  // RNE to bf16
        Wpk[idx] = (unsigned short)(u >> 16);
    }
}

// ---------- phase A: per-block bucket histogram + claim global bases ----------
__global__ void k_histB(const int* __restrict__ e32, const int* __restrict__ flag,
                        int* __restrict__ gcount, int* __restrict__ blockBase) {
    __shared__ int lc[NBUCK];
    int t = threadIdx.x;
    for (int i = t; i < NBUCK; i += 256) lc[i] = 0;
    __syncthreads();
    int isI64 = flag[0];
    int base = blockIdx.x * EPB;
    int lim = base + EPB; if (lim > N_EDGES) lim = N_EDGES;
    const long long* e64 = (const long long*)e32;
    for (int i = base + t; i < lim; i += 256) {
        int d = isI64 ? (int)e64[N_EDGES + i] : e32[N_EDGES + i];
        atomicAdd(&lc[d >> 8], 1);
    }
    __syncthreads();
    for (int b = t; b < NBUCK; b += 256)
        blockBase[blockIdx.x * NBUCK + b] = atomicAdd(&gcount[b], lc[b]);
}

// ---------- scan 391 bucket counts -> bucketStart; also row_ptr[N] ----------
__global__ void k_scanb(const int* __restrict__ gcount, int* __restrict__ bucketStart,
                        int* __restrict__ row_ptr) {
    __shared__ int s[512];
    int t = threadIdx.x;
    s[t] = (t < NBUCK) ? gcount[t] : 0;
    __syncthreads();
    for (int o = 1; o < 512; o <<= 1) {
        int v = s[t]; int a = (t >= o) ? s[t - o] : 0;
        __syncthreads(); s[t] = v + a; __syncthreads();
    }
    if (t < NBUCK) bucketStart[t + 1] = s[t];
    if (t == 0) { bucketStart[0] = 0; row_ptr[N_NODES] = N_EDGES; }
}

// ---------- phase B: scatter (src,dst) pairs into bucket-major order ----------
__global__ void k_scatterB(const int* __restrict__ e32, const int* __restrict__ flag,
                           const int* __restrict__ bucketStart, const int* __restrict__ blockBase,
                           int2* __restrict__ pairs) {
    __shared__ int lcur[NBUCK];
    int t = threadIdx.x;
    for (int b = t; b < NBUCK; b += 256)
        lcur[b] = bucketStart[b] + blockBase[blockIdx.x * NBUCK + b];
    __syncthreads();
    int isI64 = flag[0];
    int base = blockIdx.x * EPB;
    int lim = base + EPB; if (lim > N_EDGES) lim = N_EDGES;
    const long long* e64 = (const long long*)e32;
    for (int i = base + t; i < lim; i += 256) {
        int s, d;
        if (isI64) { s = (int)e64[i]; d = (int)e64[N_EDGES + i]; }
        else       { s = e32[i];      d = e32[N_EDGES + i]; }
        int pos = atomicAdd(&lcur[d >> 8], 1);
        pairs[pos] = make_int2(s, d);     // ~42-edge contiguous runs per (block,bucket)
    }
}

// ---------- phase C: per-bucket counting sort in LDS -> esrc + row_ptr ----------
__global__ void k_sortB(const int2* __restrict__ pairs, const int* __restrict__ bucketStart,
                        int* __restrict__ row_ptr, int* __restrict__ esrc) {
    __shared__ int srcb[CAP];       // packed: src | (local_dst<<20)
    __shared__ int cnt[256];
    __shared__ int scn[256];
    int t = threadIdx.x;
    int b = blockIdx.x;
    int s0 = bucketStart[b], s1 = bucketStart[b + 1];
    int n = s1 - s0; if (n > CAP) n = CAP;   // never triggers (32-sigma margin)
    cnt[t] = 0;
    __syncthreads();
    for (int i = t; i < n; i += 256) {
        int2 p = pairs[s0 + i];
        int ld = p.y & 255;
        srcb[i] = p.x | (ld << 20);
        atomicAdd(&cnt[ld], 1);
    }
    __syncthreads();
    scn[t] = cnt[t];
    __syncthreads();
    for (int o = 1; o < 256; o <<= 1) {
        int v = scn[t]; int a = (t >= o) ? scn[t - o] : 0;
        __syncthreads(); scn[t] = v + a; __syncthreads();
    }
    int excl = scn[t] - cnt[t];
    int node = b * 256 + t;
    if (node < N_NODES) row_ptr[node] = s0 + excl;
    __syncthreads();
    cnt[t] = excl;                  // reuse as cursor
    __syncthreads();
    for (int i = t; i < n; i += 256) {
        int v = srcb[i];
        int ld = v >> 20;
        int r = atomicAdd(&cnt[ld], 1);
        esrc[s0 + r] = v & 0xFFFFF; // 16KB window, single block/XCD -> L2 absorbs
    }
}

// ---------- layer-1 via MFMA: [y_rel | y_root] = x @ [Wrel1;Wroot1]^T ----------
// staging v2: per-row strips, no div/mod, zero-pad folded into strip 3.
__launch_bounds__(256, 4)
__global__ void k_gemm_mfma(const float* __restrict__ x, const unsigned short* __restrict__ Wpk,
                            unsigned short* __restrict__ y_rel, float* __restrict__ y_root) {
    __shared__ unsigned short lh[32][232];
    __shared__ unsigned short ll[32][232];
    int tid = threadIdx.x;
    int base = blockIdx.x * 32;
    int w = tid >> 6, l = tid & 63;

    // wave w stages rows 8w..8w+7; strips of 64 cols; strip 2 lanes>=37 write pad zeros
    {
        const float* xb = x + (size_t)base * DIM_IN;
        #pragma unroll
        for (int rr = 0; rr < 8; ++rr) {
            int r = w * 8 + rr;
            const float* rp = xb + (size_t)r * DIM_IN;
            #pragma unroll
            for (int s = 0; s < 3; ++s) {
                int k = s * 64 + l;
                if (s < 2 || k < DIM_IN) {
                    float f = rp[k];
                    unsigned u = __float_as_uint(f);
                    unsigned short hi = (unsigned short)(u >> 16);       // truncate
                    float fhi = __uint_as_float(u & 0xFFFF0000u);
                    float lo = f - fhi;                                   // exact residual
                    lh[r][k] = hi;
                    ll[r][k] = (unsigned short)(__float_as_uint(lo) >> 16);
                } else {                                                  // k in [165,192)
                    if (k < K_PAD) { lh[r][k] = 0; ll[r][k] = 0; }
                }
            }
        }
    }
    __syncthreads();

    int rowg = w & 1;
    int colh = w >> 1;
    int m = l & 15, kg = l >> 4;
    int arow = rowg * 16 + m;

    f32x4 acc[8];
    #pragma unroll
    for (int t = 0; t < 8; ++t) acc[t] = (f32x4){0.f, 0.f, 0.f, 0.f};

    const short8v* ap_h = (const short8v*)(&lh[arow][0]);
    const short8v* ap_l = (const short8v*)(&ll[arow][0]);
    const short8v* bp   = (const short8v*)Wpk;
    int bidx = kg * 256 + colh * 128 + m;

    #pragma unroll
    for (int kc = 0; kc < 6; ++kc) {
        short8v ah = ap_h[kc * 4 + kg];
        short8v al = ap_l[kc * 4 + kg];
        short8v bfrag[8];
        #pragma unroll
        for (int t = 0; t < 8; ++t) bfrag[t] = bp[bidx + kc * 1024 + t * 16];
        #pragma unroll
        for (int t = 0; t < 8; ++t)
            acc[t] = __builtin_amdgcn_mfma_f32_16x16x32_bf16(ah, bfrag[t], acc[t], 0, 0, 0);
        #pragma unroll
        for (int t = 0; t < 8; ++t)
            acc[t] = __builtin_amdgcn_mfma_f32_16x16x32_bf16(al, bfrag[t], acc[t], 0, 0, 0);
    }

    int orow = base + rowg * 16 + kg * 4;
    if (colh == 0) {
        #pragma unroll
        for (int t = 0; t < 8; ++t) {
            #pragma unroll
            for (int q = 0; q < 4; ++q) {
                unsigned u = __float_as_uint(acc[t][q]);
                u += 0x7FFFu + ((u >> 16) & 1u);
                y_rel[(size_t)(orow + q) * 128 + t * 16 + m] = (unsigned short)(u >> 16);
            }
        }
    } else {
        #pragma unroll
        for (int t = 0; t < 8; ++t) {
            #pragma unroll
            for (int q = 0; q < 4; ++q)
                y_root[(size_t)(orow + q) * 128 + t * 16 + m] = acc[t][q];
        }
    }
}

// ---------- fused agg v3: quarter-wave edges, 8-edge pipeline, float2 accs ----------
__launch_bounds__(256, 8)
__global__ void k_agg(const unsigned short* __restrict__ y_rel, const float* __restrict__ y_root,
                      const int* __restrict__ row_ptr, const int* __restrict__ esrc,
                      const float* __restrict__ b_rel1, const float* __restrict__ W_rel2,
                      const float* __restrict__ W_root2,
                      float* __restrict__ s_out, float* __restrict__ r_out) {
    int node = blockIdx.x * 4 + (threadIdx.x >> 6);
    int lane = threadIdx.x & 63;
    int li = lane & 15;            // column group: owns cols 8*li .. 8*li+7
    int qid = lane >> 4;           // quarter 0..3 -> edge k+qid
    const uint4* yr = (const uint4*)y_rel;

    int e0 = row_ptr[node], e1 = row_ptr[node + 1];
    float2 c0 = {0.f, 0.f}, c1 = {0.f, 0.f}, c2 = {0.f, 0.f}, c3 = {0.f, 0.f};

#define ACC4(v)                                                                   \
    { c0.x += __uint_as_float((v).x << 16); c0.y += __uint_as_float((v).x & 0xFFFF0000u); \
      c1.x += __uint_as_float((v).y << 16); c1.y += __uint_as_float((v).y & 0xFFFF0000u); \
      c2.x += __uint_as_float((v).z << 16); c2.y += __uint_as_float((v).z & 0xFFFF0000u); \
      c3.x += __uint_as_float((v).w << 16); c3.y += __uint_as_float((v).w & 0xFFFF0000u); }

    for (int eb = e0; eb < e1; eb += 64) {
        int cnt = e1 - eb; if (cnt > 64) cnt = 64;
        int ed = (eb + lane < e1) ? esrc[eb + lane] : 0;   // one coalesced load
        int k = 0;
        for (; k + 8 <= cnt; k += 8) {                     // two gathers in flight
            int sA = __shfl(ed, k + qid);
            int sB = __shfl(ed, k + 4 + qid);
            uint4 vA = yr[(size_t)sA * 16 + li];
            uint4 vB = yr[(size_t)sB * 16 + li];
            ACC4(vA); ACC4(vB);
        }
        if (k + 4 <= cnt) {
            int sA = __shfl(ed, k + qid);
            uint4 vA = yr[(size_t)sA * 16 + li];
            ACC4(vA);
            k += 4;
        }
        if (k < cnt) {                                     // 1..3 leftover edges
            int rem = cnt - k;
            int idx = k + ((qid < rem) ? qid : (rem - 1));
            int sA = __shfl(ed, idx);
            if (qid < rem) {
                uint4 vA = yr[(size_t)sA * 16 + li];
                ACC4(vA);
            }
        }
    }
#undef ACC4

    // combine quarters (lanes with same li across qid hold partial sums)
    #pragma unroll
    for (int o = 16; o <= 32; o <<= 1) {
        c0.x += __shfl_xor(c0.x, o); c0.y += __shfl_xor(c0.y, o);
        c1.x += __shfl_xor(c1.x, o); c1.y += __shfl_xor(c1.y, o);
        c2.x += __shfl_xor(c2.x, o); c2.y += __shfl_xor(c2.y, o);
        c3.x += __shfl_xor(c3.x, o); c3.y += __shfl_xor(c3.y, o);
    }

    const float4* bb = (const float4*)(b_rel1 + 8 * li);
    const float4* rt = (const float4*)(y_root + (size_t)node * 128 + 8 * li);
    const float4* w2 = (const float4*)(W_rel2 + 8 * li);
    const float4* wo = (const float4*)(W_root2 + 8 * li);
    float4 b0 = bb[0], b1 = bb[1];
    float4 r0 = rt[0], r1 = rt[1];
    float4 p0 = w2[0], p1 = w2[1];
    float4 q0 = wo[0], q1 = wo[1];
    float h0 = fmaxf(c0.x + b0.x + r0.x, 0.f), h1 = fmaxf(c0.y + b0.y + r0.y, 0.f);
    float h2 = fmaxf(c1.x + b0.z + r0.z, 0.f), h3 = fmaxf(c1.y + b0.w + r0.w, 0.f);
    float h4 = fmaxf(c2.x + b1.x + r1.x, 0.f), h5 = fmaxf(c2.y + b1.y + r1.y, 0.f);
    float h6 = fmaxf(c3.x + b1.z + r1.z, 0.f), h7 = fmaxf(c3.y + b1.w + r1.w, 0.f);
    float sd = h0 * p0.x + h1 * p0.y + h2 * p0.z + h3 * p0.w
             + h4 * p1.x + h5 * p1.y + h6 * p1.z + h7 * p1.w;
    float rd = h0 * q0.x + h1 * q0.y + h2 * q0.z + h3 * q0.w
             + h4 * q1.x + h5 * q1.y + h6 * q1.z + h7 * q1.w;
    #pragma unroll
    for (int o = 1; o <= 8; o <<= 1) {
        sd += __shfl_xor(sd, o);
        rd += __shfl_xor(rd, o);
    }
    if (lane == 0) { s_out[node] = sd; r_out[node] = rd; }
}

// ---------- final: thread-per-node, 2-deep independent accumulators ----------
__global__ void k_final(const float* __restrict__ s_in, const float* __restrict__ r_in,
                        const int* __restrict__ row_ptr, const int* __restrict__ esrc,
                        const float* __restrict__ b_rel2, float* __restrict__ out) {
    int i = blockIdx.x * blockDim.x + threadIdx.x;
    if (i < N_NODES) {
        int e0 = row_ptr[i], e1 = row_ptr[i + 1];
        float s0 = 0.f, s1 = 0.f;
        int e = e0;
        for (; e + 1 < e1; e += 2) {
            s0 += s_in[esrc[e]];           // s_in 400KB, L2-hot
            s1 += s_in[esrc[e + 1]];
        }
        if (e < e1) s0 += s_in[esrc[e]];
        float z = s0 + s1 + b_rel2[0] + r_in[i];
        out[i] = 1.f / (1.f + expf(-z));
    }
}

extern "C" void kernel_launch(void* const* d_in, const int* in_sizes, int n_in,
                              void* d_out, int out_size, void* d_ws, size_t ws_size,
                              hipStream_t stream) {
    const float* x      = (const float*)d_in[0];
    const int*   eidx   = (const int*)d_in[1];
    const float* Wrel1  = (const float*)d_in[2];
    const float* brel1  = (const float*)d_in[3];
    const float* Wroot1 = (const float*)d_in[4];
    const float* Wrel2  = (const float*)d_in[5];
    const float* brel2  = (const float*)d_in[6];
    const float* Wroot2 = (const float*)d_in[7];
    float* out = (float*)d_out;

    char* basep = (char*)d_ws;
    size_t off = 0;
    auto alloc = [&](size_t bytes) -> void* {
        off = (off + 511) & ~(size_t)511;
        void* r = basep + off;
        off += bytes;
        return r;
    };
    // --- persistent ---
    int*   flag        = (int*)alloc(4);
    unsigned short* Wpk = (unsigned short*)alloc((size_t)(K_PAD / 8) * 256 * 8 * 2);
    int*   row_ptr     = (int*)alloc((size_t)(N_NODES + 1) * 4);
    int*   esrc        = (int*)alloc((size_t)N_EDGES * 4);
    float* s_buf       = (float*)alloc((size_t)N_NODES * 4);
    float* r_buf       = (float*)alloc((size_t)N_NODES * 4);
    int*   bucketStart = (int*)alloc((size_t)(NBUCK + 1) * 4);
    int*   gcount      = (int*)alloc((size_t)NBUCK * 4);
    // --- union region: sort scratch (dead after k_sortB) vs GEMM outputs ---
    size_t union_base = (off + 511) & ~(size_t)511;
    off = union_base;
    int2*  pairs     = (int2*)alloc((size_t)N_EDGES * 8);
    int*   blockBase = (int*)alloc((size_t)NHB * NBUCK * 4);
    off = union_base;
    unsigned short* y_rel  = (unsigned short*)alloc((size_t)N_NODES * DIM_HID * 2);
    float*          y_root = (float*)alloc((size_t)N_NODES * DIM_HID * 4);

    hipLaunchKernelGGL(k_init,     dim3(193),   dim3(256), 0, stream, eidx, flag, gcount,
                       Wrel1, Wroot1, Wpk);
    hipLaunchKernelGGL(k_histB,    dim3(NHB),   dim3(256), 0, stream, eidx, flag, gcount, blockBase);
    hipLaunchKernelGGL(k_scanb,    dim3(1),     dim3(512), 0, stream, gcount, bucketStart, row_ptr);
    hipLaunchKernelGGL(k_scatterB, dim3(NHB),   dim3(256), 0, stream, eidx, flag, bucketStart, blockBase, pairs);
    hipLaunchKernelGGL(k_sortB,    dim3(NBUCK), dim3(256), 0, stream, pairs, bucketStart, row_ptr, esrc);
    hipLaunchKernelGGL(k_gemm_mfma,dim3(3125),  dim3(256), 0, stream, x, Wpk, y_rel, y_root);
    hipLaunchKernelGGL(k_agg,      dim3(25000), dim3(256), 0, stream, y_rel, y_root, row_ptr, esrc,
                       brel1, Wrel2, Wroot2, s_buf, r_buf);
    hipLaunchKernelGGL(k_final,    dim3(391),   dim3(256), 0, stream, s_buf, r_buf, row_ptr, esrc,
                       brel2, out);
}